// Round 8
// baseline (94.604 us; speedup 1.0000x reference)
//
#include <hip/hip_runtime.h>
#include <hip/hip_bf16.h>

#define T_STEPS 128
#define BATCH   2048
#define IN_F    64
#define HID     256
#define OUT_F   16
#define CH      8                  // timesteps per P-exchange group
#define TROWS   16                 // batch rows per block
#define HHALF   128                // hid columns per block (4 waves x 32)
#define NCH     (T_STEPS / CH)     // 16 groups
#define SLAB    (BATCH * OUT_F)
#define PD      4                  // x register-prefetch distance (steps)

typedef __attribute__((ext_vector_type(8))) short bf16x8;
typedef __attribute__((ext_vector_type(4))) float f32x4;
typedef unsigned short u16;
typedef unsigned int   u32;

__device__ __forceinline__ u16 f2bf(float f) {      // RNE via HW cvt (pk-fusable)
    union { __hip_bfloat16 h; u16 u; } cv;
    cv.h = __float2bfloat16(f);
    return cv.u;
}
__device__ __forceinline__ float bf2f(u16 h) {
    return __uint_as_float(((u32)h) << 16);
}
__device__ __forceinline__ bf16x8 pack8(float4 a, float4 b) {
    bf16x8 r;
    r[0] = (short)f2bf(a.x); r[1] = (short)f2bf(a.y);
    r[2] = (short)f2bf(a.z); r[3] = (short)f2bf(a.w);
    r[4] = (short)f2bf(b.x); r[5] = (short)f2bf(b.y);
    r[6] = (short)f2bf(b.z); r[7] = (short)f2bf(b.w);
    return r;
}

// Zero the spikes_mean accumulator (d_out not re-poisoned between replays).
__global__ void snn_init_kernel(float* __restrict__ out) {
    if (threadIdx.x == 0 && blockIdx.x == 0) out[BATCH * OUT_F] = 0.0f;
}

// Kernel 1: transposed-layer-1 LIF. Block = 16 rows x 128 hid, 4 waves
// (wave = 32 hid), z stays in registers; x loaded per-lane from global with
// a rolling 4-step prefetch; LDS only for the per-step P-partial exchange.
__global__ void __launch_bounds__(256, 1)
snn_l1_kernel(const float* __restrict__ x, const float* __restrict__ w1,
              const float* __restrict__ w2, u16* __restrict__ g2p,
              float* __restrict__ out)
{
    const int tid  = threadIdx.x;
    const int lane = tid & 63;
    const int wv   = tid >> 6;               // 4 waves; wave owns 32 hid
    const int hi   = lane >> 4;
    const int l15  = lane & 15;              // = batch row within tile
    const int tile = blockIdx.x & 127;       // halves of a tile: same XCD
    const int half = blockIdx.x >> 7;
    const int row0 = tile * TROWS;
    const int hbase = half * HHALF + wv * 32;

    __shared__ __attribute__((aligned(16))) float ws[2][CH][4][256];  // 64 KB
    __shared__ float sacc;
    if (tid == 0) sacc = 0.f;

    const f32x4 zf = {0.f, 0.f, 0.f, 0.f};
    const float dt_tau = (float)(0.001 * (1.0 / 0.006));       // 1/6
    const float decay  = (float)(1.0 - 0.001 * (1.0 / 0.006)); // 5/6

    // W1 as MFMA *A*-frags: A[n=hid][k], lane row n = hbase + tt*16 + l15,
    // k = kh*32 + 8*hi + i (contiguous 8 floats of w1's row).
    bf16x8 w1f[2][2];
#pragma unroll
    for (int tt = 0; tt < 2; ++tt)
#pragma unroll
        for (int kh = 0; kh < 2; ++kh) {
            const float* src = &w1[(hbase + tt * 16 + l15) * IN_F + kh * 32 + hi * 8];
            w1f[tt][kh] = pack8(*(const float4*)src, *(const float4*)(src + 4));
        }

    // W2 as layer-2 B-frag with the k<->hid permutation matching the z-frag:
    // frag elem i of lane(hi) <-> hid = hbase + (i<4 ? 4*hi+i : 16+4*hi+(i-4)).
    bf16x8 w2f;
#pragma unroll
    for (int i = 0; i < 8; ++i) {
        const int h = hbase + ((i < 4) ? (4 * hi + i) : (16 + 4 * hi + (i - 4)));
        w2f[i] = (short)f2bf(w2[l15 * HID + h]);
    }

    // Rolling x prefetch: slot j holds step t (t mod 4 == j). Per lane, step t:
    // floats [8hi,8hi+8) and [32+8hi,32+8hi+8) of row (row0+l15).
    const size_t tstride = (size_t)BATCH * IN_F;
    const float* xp[PD];
    float4 ra[PD], rb[PD], rc[PD], rd[PD];
#pragma unroll
    for (int j = 0; j < PD; ++j) {
        xp[j] = x + (size_t)j * tstride + (row0 + l15) * IN_F + hi * 8;
        ra[j] = *(const float4*)(xp[j]);
        rb[j] = *(const float4*)(xp[j] + 4);
        rc[j] = *(const float4*)(xp[j] + 32);
        rd[j] = *(const float4*)(xp[j] + 36);
    }

    f32x4 v1[2] = {zf, zf}, i1[2] = {zf, zf};
    int wcnt = 0;
    int pb = 0;
    __syncthreads();

    for (int c = 0; c < NCH; ++c) {
#pragma unroll
        for (int s = 0; s < CH; ++s) {
            const int j = s & (PD - 1);
            const int t = c * CH + s;

            // ---- layer 1 (transposed): G1T[n][m], lane: m=l15, n=4hi+r ----
            const bf16x8 xf0 = pack8(ra[j], rb[j]);
            const bf16x8 xf1 = pack8(rc[j], rd[j]);
            f32x4 g1[2];
#pragma unroll
            for (int tt = 0; tt < 2; ++tt) {
                g1[tt] = __builtin_amdgcn_mfma_f32_16x16x32_bf16(w1f[tt][0], xf0, zf, 0, 0, 0);
                g1[tt] = __builtin_amdgcn_mfma_f32_16x16x32_bf16(w1f[tt][1], xf1, g1[tt], 0, 0, 0);
            }

            // ---- refill slot j with step t+PD (uniform branch) ----
            if (t + PD < T_STEPS) {
                xp[j] += PD * tstride;
                ra[j] = *(const float4*)(xp[j]);
                rb[j] = *(const float4*)(xp[j] + 4);
                rc[j] = *(const float4*)(xp[j] + 32);
                rd[j] = *(const float4*)(xp[j] + 36);
            }

            // ---- LIF (z stays in registers as the layer-2 A-frag) ----
            u32 zi[4];
#pragma unroll
            for (int tt = 0; tt < 2; ++tt) {
                const f32x4 vd = v1[tt] + dt_tau * (i1[tt] - v1[tt]);
                bool sp[4];
#pragma unroll
                for (int r = 0; r < 4; ++r) {
                    sp[r] = vd[r] > 1.0f;
                    v1[tt][r] = sp[r] ? 0.f : vd[r];
                    wcnt += __popcll(__ballot(sp[r]));
                }
                zi[2 * tt]     = (sp[0] ? 0x3F80u : 0u) | (sp[1] ? 0x3F800000u : 0u);
                zi[2 * tt + 1] = (sp[2] ? 0x3F80u : 0u) | (sp[3] ? 0x3F800000u : 0u);
                i1[tt] = i1[tt] * decay + g1[tt];
            }
            union { u32 u[4]; bf16x8 v; } zz;
            zz.u[0] = zi[0]; zz.u[1] = zi[1]; zz.u[2] = zi[2]; zz.u[3] = zi[3];

            // ---- layer 2 partial: P[m][o] over this wave's 32 hid (K=32) ----
            const f32x4 p = __builtin_amdgcn_mfma_f32_16x16x32_bf16(zz.v, w2f, zf, 0, 0, 0);
            *(f32x4*)&ws[pb][s][wv][lane * 4] = p;
        }

        __syncthreads();   // one barrier per 8 steps

        // ---- reduce: wave wv sums 4 waves' partials for steps 2wv, 2wv+1 ----
#pragma unroll
        for (int q = 0; q < 2; ++q) {
            const int s = wv * 2 + q;
            const float* wp = &ws[pb][s][0][lane * 4];
            const f32x4 a0 = *(const f32x4*)(wp);
            const f32x4 a1 = *(const f32x4*)(wp + 256);
            const f32x4 a2 = *(const f32x4*)(wp + 512);
            const f32x4 a3 = *(const f32x4*)(wp + 768);
            const f32x4 g2 = (a0 + a1) + (a2 + a3);
            u16* dst = g2p + (size_t)half * (T_STEPS * SLAB)
                     + (size_t)(c * CH + s) * SLAB + (row0 + 4 * hi) * OUT_F + l15;
#pragma unroll
            for (int r = 0; r < 4; ++r) dst[r * OUT_F] = f2bf(g2[r]);
        }
        pb ^= 1;
    }

    // spikes: wcnt is wave-uniform -> one LDS atomic per wave, one global atomic
    if (lane == 0) atomicAdd(&sacc, (float)wcnt);
    __syncthreads();
    if (tid == 0) atomicAdd(&out[BATCH * OUT_F], sacc * (1.0f / BATCH));
}

// Kernel 2: LI recurrence + max over t; one thread per (row, out) chain.
__global__ void __launch_bounds__(128)
snn_li_kernel(const u16* __restrict__ g2p, float* __restrict__ out)
{
    const int gid = blockIdx.x * 128 + threadIdx.x;    // 0..32767
    const u16* p0 = g2p + gid;
    const u16* p1 = p0 + (size_t)T_STEPS * SLAB;
    const float dt_tau = (float)(0.001 * (1.0 / 0.006));
    const float decay  = (float)(1.0 - 0.001 * (1.0 / 0.006));
    float v2 = 0.f, i2 = 0.f, ymax = -1e30f;
#pragma unroll 8
    for (int t = 0; t < T_STEPS; ++t) {
        const size_t o = (size_t)t * SLAB;
        const float g = bf2f(p0[o]) + bf2f(p1[o]);
        v2 = fmaf(dt_tau, i2 - v2, v2);   // uses old i2, matches reference
        ymax = fmaxf(ymax, v2);
        i2 = i2 * decay + g;
    }
    out[gid] = ymax;
}

extern "C" void kernel_launch(void* const* d_in, const int* in_sizes, int n_in,
                              void* d_out, int out_size, void* d_ws, size_t ws_size,
                              hipStream_t stream) {
    const float* x  = (const float*)d_in[0];
    const float* w1 = (const float*)d_in[1];
    const float* w2 = (const float*)d_in[2];
    float* out = (float*)d_out;
    u16* g2p = (u16*)d_ws;   // 2 halves x 128 t x 32768 bf16 = 16 MB

    hipLaunchKernelGGL(snn_init_kernel, dim3(1), dim3(64), 0, stream, out);
    hipLaunchKernelGGL(snn_l1_kernel, dim3(256), dim3(256), 0, stream,
                       x, w1, w2, g2p, out);
    hipLaunchKernelGGL(snn_li_kernel, dim3(BATCH * OUT_F / 128), dim3(128), 0,
                       stream, g2p, out);
}